// Round 1
// baseline (649.416 us; speedup 1.0000x reference)
//
#include <hip/hip_runtime.h>

typedef __attribute__((ext_vector_type(8))) short short8;
typedef __attribute__((ext_vector_type(4))) float f32x4;
typedef __attribute__((ext_vector_type(4))) unsigned short us4;

#define MFMA16(a,b,c) __builtin_amdgcn_mfma_f32_16x16x32_bf16((a),(b),(c),0,0,0)

__device__ __forceinline__ unsigned short f2bf(float f) {
  union { float f; unsigned u; } v; v.f = f;
  return (unsigned short)((v.u + 0x7fffu + ((v.u >> 16) & 1u)) >> 16);
}
__device__ __forceinline__ float bf2f(unsigned short h) {
  union { unsigned u; float f; } v; v.u = ((unsigned)h) << 16;
  return v.f;
}

// ---------------- prep: weights fp32 -> bf16, N-major (transposed) ----------
// wtc  [29][64][192]   : wtc[(tg*64+n)*192+c] = w_br[j][c][n]
// w1t  [80][320]       : w1t[h*320+k] = w_att1[k][h]
// w2t  [320][96]       : w2t[f*96+k]  = k<80 ? w_att2[k][f] : 0
// wot  [320][320]      : wot[g*320+f] = w_out[f][g]
// bcat [320]           : conv biases concatenated (fp32)
__global__ __launch_bounds__(256) void k_prep(
    const float* __restrict__ w1, const float* __restrict__ w2,
    const float* __restrict__ w3, const float* __restrict__ w4,
    const float* __restrict__ w5,
    const float* __restrict__ b1, const float* __restrict__ b2,
    const float* __restrict__ b3, const float* __restrict__ b4,
    const float* __restrict__ b5,
    const float* __restrict__ wa1, const float* __restrict__ wa2,
    const float* __restrict__ wo,
    unsigned short* __restrict__ wtc, unsigned short* __restrict__ w1t,
    unsigned short* __restrict__ w2t, unsigned short* __restrict__ wot,
    float* __restrict__ bcat)
{
  int i = blockIdx.x * 256 + threadIdx.x;
  if (i < 356352) {                       // conv weights
    int c = i % 192; int rest = i / 192; int n = rest & 63; int tg = rest >> 6;
    const float* w; int j;
    if (tg < 3)       { w = w1; j = tg; }
    else if (tg < 6)  { w = w2; j = tg - 3; }
    else if (tg < 11) { w = w3; j = tg - 6; }
    else if (tg < 20) { w = w4; j = tg - 11; }
    else              { w = w5; j = tg - 20; }
    wtc[i] = f2bf(w[(j * 192 + c) * 64 + n]);
    return;
  }
  i -= 356352;
  if (i < 25600) { int k = i % 320, h = i / 320; w1t[i] = f2bf(wa1[k * 80 + h]); return; }
  i -= 25600;
  if (i < 30720) { int k = i % 96, f = i / 96;
    w2t[i] = (k < 80) ? f2bf(wa2[k * 320 + f]) : (unsigned short)0; return; }
  i -= 30720;
  if (i < 102400) { int f = i % 320, g = i / 320; wot[i] = f2bf(wo[f * 320 + g]); return; }
  i -= 102400;
  if (i < 320) {
    float v;
    if (i < 64)       v = b1[i];
    else if (i < 128) v = b2[i - 64];
    else if (i < 192) v = b3[i - 128];
    else if (i < 256) v = b4[i - 192];
    else              v = b5[i - 256];
    bcat[i] = v;
  }
}

// ---------------- conv: 5 causal dilated branches -> xc bf16 [M][320] -------
// Block = 64 rows (one batch item: 4096 % 64 == 0), 4 waves x 16-col slices.
// LDS stages rows [t0-96, t0+64) x 192ch bf16, stride 200 (+8 pad).
__global__ __launch_bounds__(256) void k_conv(
    const float* __restrict__ x, const unsigned short* __restrict__ wtc,
    const float* __restrict__ bcat, unsigned short* __restrict__ xc)
{
  __shared__ unsigned short xs[160 * 200];
  int bid = blockIdx.x;
  bid = (bid & 7) * 256 + (bid >> 3);          // XCD swizzle (2048 % 8 == 0)
  const int m0 = bid * 64;
  const int b  = m0 >> 12;
  const int t0 = m0 & 4095;
  const int tid = threadIdx.x;

  const float* xb = x + (size_t)b * 4096 * 192;
  for (int c = tid; c < 160 * 48; c += 256) {
    int r = c / 48, f = c - r * 48;
    int tp = t0 - 96 + r;
    float4 v = make_float4(0.f, 0.f, 0.f, 0.f);
    if (tp >= 0) v = *(const float4*)(xb + (size_t)tp * 192 + f * 4);
    us4 o = { f2bf(v.x), f2bf(v.y), f2bf(v.z), f2bf(v.w) };
    *(us4*)(&xs[r * 200 + f * 4]) = o;
  }
  __syncthreads();

  const int wid = tid >> 6, lane = tid & 63;
  const int lg = lane >> 4, lr = lane & 15;
  const int KT[5] = {3, 3, 5, 9, 9};
  const int DL[5] = {1, 2, 4, 8, 12};
  const int TB[5] = {0, 3, 6, 11, 20};
  const f32x4 fz = {0.f, 0.f, 0.f, 0.f};

  for (int br = 0; br < 5; ++br) {
    f32x4 acc[4] = {fz, fz, fz, fz};
    const int kt = KT[br], dl = DL[br];
    for (int j = 0; j < kt; ++j) {
      const int roff = 96 - dl * (kt - 1 - j);   // causal: x[t - d*(k-1-j)]
      const unsigned short* wr =
          wtc + ((size_t)(TB[br] + j) * 64 + wid * 16 + lr) * 192 + lg * 8;
      const unsigned short* xr = &xs[(roff + lr) * 200 + lg * 8];
      #pragma unroll
      for (int ks = 0; ks < 6; ++ks) {
        short8 bf = *(const short8*)(wr + ks * 32);
        #pragma unroll
        for (int fm = 0; fm < 4; ++fm) {
          short8 af = *(const short8*)(xr + fm * 16 * 200 + ks * 32);
          acc[fm] = MFMA16(af, bf, acc[fm]);
        }
      }
    }
    const float bias = bcat[br * 64 + wid * 16 + lr];
    unsigned short* dst = xc + (size_t)(m0 + lg * 4) * 320 + br * 64 + wid * 16 + lr;
    #pragma unroll
    for (int fm = 0; fm < 4; ++fm)
      #pragma unroll
      for (int rg = 0; rg < 4; ++rg) {
        float v = acc[fm][rg] + bias;
        v = v > 0.f ? v : 0.f;
        dst[(size_t)(fm * 16 + rg) * 320] = f2bf(v);
      }
  }
}

// ---------------- gate: att1->att2->xa, xa written in-place into xc --------
__global__ __launch_bounds__(256) void k_gate(
    unsigned short* __restrict__ xc, const unsigned short* __restrict__ w1t,
    const unsigned short* __restrict__ w2t,
    const float* __restrict__ ba1, const float* __restrict__ ba2)
{
  __shared__ unsigned short a1[64 * 104];   // att1, K padded 80->96 (+8 pad)
  __shared__ unsigned short bt[320 * 40];   // B tile, K=32 (+8 pad)
  const int m0 = blockIdx.x * 64;
  const int tid = threadIdx.x;
  const int wid = tid >> 6, lane = tid & 63, lg = lane >> 4, lr = lane & 15;
  const f32x4 fz = {0.f, 0.f, 0.f, 0.f};

  for (int c = tid; c < 64 * 16; c += 256)          // zero K-pad cols 80..95
    a1[(c >> 4) * 104 + 80 + (c & 15)] = 0;

  // phase 1: att1 = relu(xc @ W1 + b1), A-frags straight from global xc
  f32x4 acc1[5] = {fz, fz, fz, fz, fz};
  const unsigned short* arow = xc + (size_t)(m0 + wid * 16 + lr) * 320 + lg * 8;
  for (int ks = 0; ks < 10; ++ks) {
    __syncthreads();
    for (int c = tid; c < 320; c += 256) {
      int n = c >> 2, ko = (c & 3) * 8;
      *(short8*)(&bt[n * 40 + ko]) = *(const short8*)(w1t + n * 320 + ks * 32 + ko);
    }
    __syncthreads();
    short8 af = *(const short8*)(arow + ks * 32);
    #pragma unroll
    for (int nf = 0; nf < 5; ++nf) {
      short8 bf = *(const short8*)(&bt[(nf * 16 + lr) * 40 + lg * 8]);
      acc1[nf] = MFMA16(af, bf, acc1[nf]);
    }
  }
  #pragma unroll
  for (int nf = 0; nf < 5; ++nf) {
    float bias = ba1[nf * 16 + lr];
    #pragma unroll
    for (int rg = 0; rg < 4; ++rg) {
      float v = acc1[nf][rg] + bias;
      v = v > 0.f ? v : 0.f;
      a1[(wid * 16 + lg * 4 + rg) * 104 + nf * 16 + lr] = f2bf(v);
    }
  }
  __syncthreads();

  // phase 2: att2 = sigmoid(att1 @ W2 + b2); xa = xc*att2 in-place
  f32x4 acc2[20];
  #pragma unroll
  for (int i = 0; i < 20; ++i) acc2[i] = fz;
  for (int ks = 0; ks < 3; ++ks) {
    if (ks) __syncthreads();
    for (int c = tid; c < 1280; c += 256) {
      int n = c >> 2, ko = (c & 3) * 8;
      *(short8*)(&bt[n * 40 + ko]) = *(const short8*)(w2t + n * 96 + ks * 32 + ko);
    }
    __syncthreads();
    short8 af = *(const short8*)(&a1[(wid * 16 + lr) * 104 + ks * 32 + lg * 8]);
    #pragma unroll
    for (int nf = 0; nf < 20; ++nf) {
      short8 bf = *(const short8*)(&bt[(nf * 16 + lr) * 40 + lg * 8]);
      acc2[nf] = MFMA16(af, bf, acc2[nf]);
    }
  }
  unsigned short* xrow = xc + (size_t)(m0 + wid * 16) * 320;
  #pragma unroll
  for (int nf = 0; nf < 20; ++nf) {
    float bias = ba2[nf * 16 + lr];
    #pragma unroll
    for (int rg = 0; rg < 4; ++rg) {
      float v = acc2[nf][rg] + bias;
      float s = 1.f / (1.f + __expf(-v));
      size_t idx = (size_t)(lg * 4 + rg) * 320 + nf * 16 + lr;
      float xv = bf2f(xrow[idx]);      // same lane reads then writes: safe
      xrow[idx] = f2bf(xv * s);
    }
  }
}

// ---------------- out: out = xa @ W_out + b_out (fp32 store) ----------------
__global__ __launch_bounds__(256) void k_out(
    const unsigned short* __restrict__ xa, const unsigned short* __restrict__ wot,
    const float* __restrict__ bo, float* __restrict__ out)
{
  __shared__ unsigned short bt[320 * 40];
  const int m0 = blockIdx.x * 64;
  const int tid = threadIdx.x;
  const int wid = tid >> 6, lane = tid & 63, lg = lane >> 4, lr = lane & 15;
  const f32x4 fz = {0.f, 0.f, 0.f, 0.f};
  f32x4 acc[20];
  #pragma unroll
  for (int i = 0; i < 20; ++i) acc[i] = fz;

  const unsigned short* arow = xa + (size_t)(m0 + wid * 16 + lr) * 320 + lg * 8;
  for (int ks = 0; ks < 10; ++ks) {
    if (ks) __syncthreads();
    for (int c = tid; c < 1280; c += 256) {
      int n = c >> 2, ko = (c & 3) * 8;
      *(short8*)(&bt[n * 40 + ko]) = *(const short8*)(wot + n * 320 + ks * 32 + ko);
    }
    __syncthreads();
    short8 af = *(const short8*)(arow + ks * 32);
    #pragma unroll
    for (int nf = 0; nf < 20; ++nf) {
      short8 bf = *(const short8*)(&bt[(nf * 16 + lr) * 40 + lg * 8]);
      acc[nf] = MFMA16(af, bf, acc[nf]);
    }
  }
  float* orow = out + (size_t)(m0 + wid * 16) * 320;
  #pragma unroll
  for (int nf = 0; nf < 20; ++nf) {
    float bias = bo[nf * 16 + lr];
    #pragma unroll
    for (int rg = 0; rg < 4; ++rg)
      orow[(size_t)(lg * 4 + rg) * 320 + nf * 16 + lr] = acc[nf][rg] + bias;
  }
}

// ---------------- host ------------------------------------------------------
extern "C" void kernel_launch(void* const* d_in, const int* in_sizes, int n_in,
                              void* d_out, int out_size, void* d_ws, size_t ws_size,
                              hipStream_t stream) {
  const float* x    = (const float*)d_in[0];
  const float* w_b1 = (const float*)d_in[1];  const float* b_b1 = (const float*)d_in[2];
  const float* w_b2 = (const float*)d_in[3];  const float* b_b2 = (const float*)d_in[4];
  const float* w_b3 = (const float*)d_in[5];  const float* b_b3 = (const float*)d_in[6];
  const float* w_b4 = (const float*)d_in[7];  const float* b_b4 = (const float*)d_in[8];
  const float* w_b5 = (const float*)d_in[9];  const float* b_b5 = (const float*)d_in[10];
  const float* wa1  = (const float*)d_in[11]; const float* ba1  = (const float*)d_in[12];
  const float* wa2  = (const float*)d_in[13]; const float* ba2  = (const float*)d_in[14];
  const float* wo   = (const float*)d_in[15]; const float* bo   = (const float*)d_in[16];

  char* ws = (char*)d_ws;
  unsigned short* xc  = (unsigned short*)(ws);              // 131072*320*2 = 83,886,080
  unsigned short* wtc = (unsigned short*)(ws + 83886080);   // 712,704
  unsigned short* w1t = (unsigned short*)(ws + 84598784);   // 51,200
  unsigned short* w2t = (unsigned short*)(ws + 84649984);   // 61,440
  unsigned short* wot = (unsigned short*)(ws + 84711424);   // 204,800
  float*          bct = (float*)         (ws + 84916224);   // 1,280  (end 84,917,504)

  k_prep<<<2014, 256, 0, stream>>>(w_b1, w_b2, w_b3, w_b4, w_b5,
                                   b_b1, b_b2, b_b3, b_b4, b_b5,
                                   wa1, wa2, wo, wtc, w1t, w2t, wot, bct);
  k_conv<<<2048, 256, 0, stream>>>(x, wtc, bct, xc);
  k_gate<<<2048, 256, 0, stream>>>(xc, w1t, w2t, ba1, ba2);
  k_out <<<2048, 256, 0, stream>>>(xc, wot, bo, (float*)d_out);
}